// Round 6
// baseline (74.949 us; speedup 1.0000x reference)
//
#include <hip/hip_runtime.h>

// Single-dispatch AUCM loss: round-5 pair-tiled kernel (known good, 62.9us)
// + last-block-arrival finalize folded in (removes the fin dispatch).
//
// Grid = 64 j-blocks x 16 i-tiles = 1024 blocks x 256 threads. Each block:
//   - loads its 1024-element i-tile (int4/float4),
//   - compacts positives (a_i = 1-p_i) into LDS via deterministic shfl scan,
//   - thread owns j = jb*256+tid, accumulates relu(a_i + p_j) over the tile's
//     positives (wave-uniform LDS broadcasts, conflict-free),
//   - jb==0 blocks also compute per-tile moments in double.
// Publication: plain stores of partials, ordered by a RELEASE fetch_add on a
// MODULE-SCOPE counter (not in ws -> no poison issue, no reset dispatch).
// Arrival detection is monotonic: each launch adds exactly 1024, so the last
// arriver of this launch sees old % 1024 == 1023 regardless of start value.
// The ONE last block issues the single agent-scope ACQUIRE fence (R4 lesson:
// per-block ACQ_REL = ~256 XCD-L2 invalidations = L2 thrash) and finalizes
// with summation order bit-identical to the old fin kernel.
//
// Math: with a_i = 1 - p_i over positives, n_j = p_j over negatives,
//   loss = [ Nn*Sum(a^2) + 2*Sum(a)*Sum(n) + P*Sum(n^2)       (squared, O(N))
//            + margin * Sum_{i,j} relu(a_i + n_j) ] / (P*Nn)  (pairwise)
//
// ws layout (all slots written before read — 0xAA-poison safe):
//   [0    .. 8192)  double reluPart[1024]
//   [8192 .. 9216)  double momPart[16][8]  (sumA, sumA2, sumN, sumN2, cnt)

#define TILE  1024
#define NTIL  16     // 16 * 1024 = 16384
#define NJB   64     // 64 * 256  = 16384
#define NBLK  (NJB * NTIL)

__device__ unsigned int g_arrive = 0;   // module-scope: survives ws poison

__device__ __forceinline__ double wave_reduce_f64(double v) {
    #pragma unroll
    for (int off = 32; off > 0; off >>= 1) v += __shfl_xor(v, off, 64);
    return v;
}

// ---------------------------------------------------------------------------
__global__ __launch_bounds__(256)
void aucm_pair(const float* __restrict__ preds,
               const int* __restrict__ tgt,
               int n,
               double* __restrict__ reluPart,   // [1024]
               double* __restrict__ momPart,    // [16][8]
               float* __restrict__ out, float margin)
{
    __shared__ __align__(16) float sP[TILE];
    __shared__ int sWaveC[4];
    __shared__ double sRed[4][6];
    __shared__ int sLast;

    const int tid  = threadIdx.x;
    const int lane = tid & 63;
    const int wave = tid >> 6;
    const int b    = blockIdx.x;
    const int jb   = b & (NJB - 1);   // j-block (0..63)
    const int it   = b >> 6;          // i-tile  (0..15)
    const bool doMom = (jb == 0);

    // ---- Load my 4 contiguous i-tile elements (vectorized, coalesced).
    const int base = it * TILE + (tid << 2);
    const int4   t4 = *reinterpret_cast<const int4*>(&tgt[base]);
    const float4 p4 = *reinterpret_cast<const float4*>(&preds[base]);
    const int f0 = (t4.x == 1), f1 = (t4.y == 1),
              f2 = (t4.z == 1), f3 = (t4.w == 1);
    const int c = f0 + f1 + f2 + f3;

    // ---- Deterministic compaction offset: shfl inclusive scan + wave offs.
    int v = c;
    #pragma unroll
    for (int d = 1; d < 64; d <<= 1) {
        const int t = __shfl_up(v, d, 64);
        if (lane >= d) v += t;
    }
    if (lane == 63) sWaveC[wave] = v;
    __syncthreads();
    int wOff = 0;
    #pragma unroll
    for (int w = 0; w < 4; ++w) if (w < wave) wOff += sWaveC[w];
    const int cntP = sWaveC[0] + sWaveC[1] + sWaveC[2] + sWaveC[3];

    int g = wOff + v - c;              // exclusive start, element order kept
    if (f0) sP[g++] = 1.0f - p4.x;
    if (f1) sP[g++] = 1.0f - p4.y;
    if (f2) sP[g++] = 1.0f - p4.z;
    if (f3) sP[g++] = 1.0f - p4.w;

    // ---- Per-tile moments (only the 16 jb==0 blocks), all in double.
    double mA = 0, mA2 = 0, mN = 0, mN2 = 0;
    if (doMom) {
        const float pv[4] = { p4.x, p4.y, p4.z, p4.w };
        const int   fv[4] = { f0, f1, f2, f3 };
        #pragma unroll
        for (int u = 0; u < 4; ++u) {
            if (fv[u]) { const double a = 1.0 - (double)pv[u]; mA += a; mA2 += a * a; }
            else       { const double p = (double)pv[u];       mN += p; mN2 += p * p; }
        }
    }
    __syncthreads();

    // ---- Relu pair loop: thread owns j = jb*256 + tid (j < n always).
    const int j = (jb << 8) + tid;
    double accd = 0.0;
    if (tgt[j] == 0) {
        const float pj = preds[j];
        int k = 0;
        while (k < cntP) {
            const int end = min(cntP, k + 64);
            float a0 = 0.f, a1 = 0.f;
            for (; k + 8 <= end; k += 8) {
                const float4 v0 = *reinterpret_cast<const float4*>(&sP[k]);
                const float4 v1 = *reinterpret_cast<const float4*>(&sP[k + 4]);
                a0 += fmaxf(v0.x + pj, 0.f);
                a1 += fmaxf(v0.y + pj, 0.f);
                a0 += fmaxf(v0.z + pj, 0.f);
                a1 += fmaxf(v0.w + pj, 0.f);
                a0 += fmaxf(v1.x + pj, 0.f);
                a1 += fmaxf(v1.y + pj, 0.f);
                a0 += fmaxf(v1.z + pj, 0.f);
                a1 += fmaxf(v1.w + pj, 0.f);
            }
            float at = a0 + a1;
            for (; k < end; ++k) at += fmaxf(sP[k] + pj, 0.f);
            accd += (double)at;        // chunked double flush (<=64 f32 adds)
        }
    }

    double r = wave_reduce_f64(accd);
    if (lane == 0) sRed[wave][0] = r;
    if (doMom) {
        const double rA  = wave_reduce_f64(mA);
        const double rA2 = wave_reduce_f64(mA2);
        const double rN  = wave_reduce_f64(mN);
        const double rN2 = wave_reduce_f64(mN2);
        if (lane == 0) {
            sRed[wave][1] = rA; sRed[wave][2] = rA2;
            sRed[wave][3] = rN; sRed[wave][4] = rN2;
        }
    }
    __syncthreads();
    if (tid == 0) {
        reluPart[b] = sRed[0][0] + sRed[1][0] + sRed[2][0] + sRed[3][0];
        if (doMom) {
            double tA = 0, tA2 = 0, tN = 0, tN2 = 0;
            #pragma unroll
            for (int w = 0; w < 4; ++w) {
                tA += sRed[w][1]; tA2 += sRed[w][2];
                tN += sRed[w][3]; tN2 += sRed[w][4];
            }
            momPart[it * 8 + 0] = tA;  momPart[it * 8 + 1] = tA2;
            momPart[it * 8 + 2] = tN;  momPart[it * 8 + 3] = tN2;
            momPart[it * 8 + 4] = (double)cntP;
        }
        // Release-arrive: orders the partial stores above. Monotonic counter
        // (module global, +1024 per launch): last arriver has old%1024==1023.
        const unsigned int old = __hip_atomic_fetch_add(
            &g_arrive, 1u, __ATOMIC_RELEASE, __HIP_MEMORY_SCOPE_AGENT);
        sLast = ((old & (NBLK - 1)) == NBLK - 1);
    }
    __syncthreads();

    if (sLast) {
        // The ONE acquire in the whole kernel.
        if (tid == 0)
            __builtin_amdgcn_fence(__ATOMIC_ACQUIRE, "agent");
        __syncthreads();

        // ---- Finalize: summation order identical to the old fin kernel. ----
        double rr = reluPart[tid] + reluPart[tid + 256]
                  + reluPart[tid + 512] + reluPart[tid + 768];
        rr = wave_reduce_f64(rr);
        __shared__ double sRedR[4];
        if (lane == 0) sRedR[wave] = rr;

        double fA = 0, fA2 = 0, fN = 0, fN2 = 0, pc = 0;
        if (tid < NTIL) {
            fA  = momPart[tid * 8 + 0]; fA2 = momPart[tid * 8 + 1];
            fN  = momPart[tid * 8 + 2]; fN2 = momPart[tid * 8 + 3];
            pc  = momPart[tid * 8 + 4];
        }
        if (wave == 0) {
            fA  = wave_reduce_f64(fA);  fA2 = wave_reduce_f64(fA2);
            fN  = wave_reduce_f64(fN);  fN2 = wave_reduce_f64(fN2);
            pc  = wave_reduce_f64(pc);
        }
        __syncthreads();
        if (tid == 0) {
            const double tR = sRedR[0] + sRedR[1] + sRedR[2] + sRedR[3];
            const double P  = pc;
            const double Nn = (double)n - P;
            const double sq = Nn * fA2 + 2.0 * fA * fN + P * fN2;
            out[0] = (float)((sq + (double)margin * tR) / (P * Nn));
        }
    }
}

// ---------------------------------------------------------------------------
extern "C" void kernel_launch(void* const* d_in, const int* in_sizes, int n_in,
                              void* d_out, int out_size, void* d_ws, size_t ws_size,
                              hipStream_t stream) {
    const float* preds = (const float*)d_in[0];
    const int*   tgt   = (const int*)d_in[1];
    float* out = (float*)d_out;
    const int n = in_sizes[0];   // 16384 = NTIL*TILE = NJB*256

    char* ws = (char*)d_ws;
    double* reluPart = (double*)(ws + 0);
    double* momPart  = (double*)(ws + 8192);

    aucm_pair<<<NBLK, 256, 0, stream>>>(preds, tgt, n, reluPart, momPart,
                                        out, 1.0f /*MARGIN*/);
}

// Round 7
// 61.572 us; speedup vs baseline: 1.2173x; 1.2173x over previous
//
#include <hip/hip_runtime.h>

// Two-dispatch AUCM loss, pair-tiled (round-5 structure — best measured).
// Change vs R5: the j-side loads (tgt[j], preds[j]) are hoisted to kernel
// entry so all four global loads are in flight together and their latency
// hides under the compaction scan (they were previously issued after the
// barrier, exposing ~200-900 cy of L2/HBM latency at only 4 waves/SIMD).
//
// Lessons encoded from R1/R3/R4/R6: cooperative grid.sync ~25us; any
// cross-block arrival/finalize protocol (even release-only + single acquire)
// costs more than a dispatch boundary (~3us). Keep 2 dispatches.
//
// Math: with a_i = 1 - p_i over positives, n_j = p_j over negatives,
//   loss = [ Nn*Sum(a^2) + 2*Sum(a)*Sum(n) + P*Sum(n^2)       (squared, O(N))
//            + margin * Sum_{i,j} relu(a_i + n_j) ] / (P*Nn)  (pairwise)
//
// No ws zero-init: every ws slot read by kernel B is written by kernel A.
// ws layout:
//   [0    .. 8192)  double reluPart[1024]
//   [8192 .. 9216)  double momPart[16][8]  (sumA, sumA2, sumN, sumN2, cnt)

#define TILE  1024
#define NTIL  16     // 16 * 1024 = 16384
#define NJB   64     // 64 * 256  = 16384

__device__ __forceinline__ double wave_reduce_f64(double v) {
    #pragma unroll
    for (int off = 32; off > 0; off >>= 1) v += __shfl_xor(v, off, 64);
    return v;
}

// ---------------------------------------------------------------------------
__global__ __launch_bounds__(256)
void aucm_pair(const float* __restrict__ preds,
               const int* __restrict__ tgt,
               int n,
               double* __restrict__ reluPart,   // [1024]
               double* __restrict__ momPart)    // [16][8]
{
    __shared__ __align__(16) float sP[TILE];
    __shared__ int sWaveC[4];
    __shared__ double sRed[4][6];

    const int tid  = threadIdx.x;
    const int lane = tid & 63;
    const int wave = tid >> 6;
    const int b    = blockIdx.x;
    const int jb   = b & (NJB - 1);   // j-block (0..63)
    const int it   = b >> 6;          // i-tile  (0..15)
    const bool doMom = (jb == 0);

    // ---- Issue ALL global loads up front (latency overlap with the scan).
    const int base = it * TILE + (tid << 2);
    const int4   t4 = *reinterpret_cast<const int4*>(&tgt[base]);
    const float4 p4 = *reinterpret_cast<const float4*>(&preds[base]);
    const int j  = (jb << 8) + tid;      // j < n always (64*256 = n)
    const int   tj = tgt[j];             // hoisted: in flight during scan
    const float pj = preds[j];           // hoisted: in flight during scan

    const int f0 = (t4.x == 1), f1 = (t4.y == 1),
              f2 = (t4.z == 1), f3 = (t4.w == 1);
    const int c = f0 + f1 + f2 + f3;

    // ---- Deterministic compaction offset: shfl inclusive scan + wave offs.
    int v = c;
    #pragma unroll
    for (int d = 1; d < 64; d <<= 1) {
        const int t = __shfl_up(v, d, 64);
        if (lane >= d) v += t;
    }
    if (lane == 63) sWaveC[wave] = v;
    __syncthreads();
    int wOff = 0;
    #pragma unroll
    for (int w = 0; w < 4; ++w) if (w < wave) wOff += sWaveC[w];
    const int cntP = sWaveC[0] + sWaveC[1] + sWaveC[2] + sWaveC[3];

    int g = wOff + v - c;              // exclusive start, element order kept
    if (f0) sP[g++] = 1.0f - p4.x;
    if (f1) sP[g++] = 1.0f - p4.y;
    if (f2) sP[g++] = 1.0f - p4.z;
    if (f3) sP[g++] = 1.0f - p4.w;

    // ---- Per-tile moments (only the 16 jb==0 blocks), all in double.
    double mA = 0, mA2 = 0, mN = 0, mN2 = 0;
    if (doMom) {
        const float pv[4] = { p4.x, p4.y, p4.z, p4.w };
        const int   fv[4] = { f0, f1, f2, f3 };
        #pragma unroll
        for (int u = 0; u < 4; ++u) {
            if (fv[u]) { const double a = 1.0 - (double)pv[u]; mA += a; mA2 += a * a; }
            else       { const double p = (double)pv[u];       mN += p; mN2 += p * p; }
        }
    }
    __syncthreads();

    // ---- Relu pair loop: thread owns j (operands already in registers).
    double accd = 0.0;
    if (tj == 0) {
        int k = 0;
        while (k < cntP) {
            const int end = min(cntP, k + 64);
            float a0 = 0.f, a1 = 0.f;
            for (; k + 8 <= end; k += 8) {
                const float4 v0 = *reinterpret_cast<const float4*>(&sP[k]);
                const float4 v1 = *reinterpret_cast<const float4*>(&sP[k + 4]);
                a0 += fmaxf(v0.x + pj, 0.f);
                a1 += fmaxf(v0.y + pj, 0.f);
                a0 += fmaxf(v0.z + pj, 0.f);
                a1 += fmaxf(v0.w + pj, 0.f);
                a0 += fmaxf(v1.x + pj, 0.f);
                a1 += fmaxf(v1.y + pj, 0.f);
                a0 += fmaxf(v1.z + pj, 0.f);
                a1 += fmaxf(v1.w + pj, 0.f);
            }
            float at = a0 + a1;
            for (; k < end; ++k) at += fmaxf(sP[k] + pj, 0.f);
            accd += (double)at;        // chunked double flush (<=64 f32 adds)
        }
    }

    double r = wave_reduce_f64(accd);
    if (lane == 0) sRed[wave][0] = r;
    if (doMom) {
        const double rA  = wave_reduce_f64(mA);
        const double rA2 = wave_reduce_f64(mA2);
        const double rN  = wave_reduce_f64(mN);
        const double rN2 = wave_reduce_f64(mN2);
        if (lane == 0) {
            sRed[wave][1] = rA; sRed[wave][2] = rA2;
            sRed[wave][3] = rN; sRed[wave][4] = rN2;
        }
    }
    __syncthreads();
    if (tid == 0) {
        reluPart[b] = sRed[0][0] + sRed[1][0] + sRed[2][0] + sRed[3][0];
        if (doMom) {
            double tA = 0, tA2 = 0, tN = 0, tN2 = 0;
            #pragma unroll
            for (int w = 0; w < 4; ++w) {
                tA += sRed[w][1]; tA2 += sRed[w][2];
                tN += sRed[w][3]; tN2 += sRed[w][4];
            }
            momPart[it * 8 + 0] = tA;  momPart[it * 8 + 1] = tA2;
            momPart[it * 8 + 2] = tN;  momPart[it * 8 + 3] = tN2;
            momPart[it * 8 + 4] = (double)cntP;
        }
    }
}

// ---------------------------------------------------------------------------
__global__ __launch_bounds__(256)
void aucm_fin(const double* __restrict__ reluPart,
              const double* __restrict__ momPart,
              int n, float* __restrict__ out, float margin)
{
    __shared__ double sRedR[4];
    const int tid  = threadIdx.x;
    const int lane = tid & 63;
    const int wave = tid >> 6;

    // Relu partials: 1024 doubles, 4 per thread (deterministic order).
    double r = reluPart[tid] + reluPart[tid + 256]
             + reluPart[tid + 512] + reluPart[tid + 768];
    r = wave_reduce_f64(r);
    if (lane == 0) sRedR[wave] = r;

    // Moments: 16 tiles x 5 values, handled by wave 0 lanes 0..15.
    double mA = 0, mA2 = 0, mN = 0, mN2 = 0, pc = 0;
    if (tid < NTIL) {
        mA  = momPart[tid * 8 + 0]; mA2 = momPart[tid * 8 + 1];
        mN  = momPart[tid * 8 + 2]; mN2 = momPart[tid * 8 + 3];
        pc  = momPart[tid * 8 + 4];
    }
    if (wave == 0) {
        mA  = wave_reduce_f64(mA);  mA2 = wave_reduce_f64(mA2);
        mN  = wave_reduce_f64(mN);  mN2 = wave_reduce_f64(mN2);
        pc  = wave_reduce_f64(pc);
    }
    __syncthreads();
    if (tid == 0) {
        const double tR = sRedR[0] + sRedR[1] + sRedR[2] + sRedR[3];
        const double P  = pc;
        const double Nn = (double)n - P;
        const double sq = Nn * mA2 + 2.0 * mA * mN + P * mN2;
        out[0] = (float)((sq + (double)margin * tR) / (P * Nn));
    }
}

// ---------------------------------------------------------------------------
extern "C" void kernel_launch(void* const* d_in, const int* in_sizes, int n_in,
                              void* d_out, int out_size, void* d_ws, size_t ws_size,
                              hipStream_t stream) {
    const float* preds = (const float*)d_in[0];
    const int*   tgt   = (const int*)d_in[1];
    float* out = (float*)d_out;
    const int n = in_sizes[0];   // 16384 = NTIL*TILE = NJB*256

    char* ws = (char*)d_ws;
    double* reluPart = (double*)(ws + 0);
    double* momPart  = (double*)(ws + 8192);

    aucm_pair<<<NJB * NTIL, 256, 0, stream>>>(preds, tgt, n, reluPart, momPart);
    aucm_fin<<<1, 256, 0, stream>>>(reluPart, momPart, n, out, 1.0f /*MARGIN*/);
}

// Round 8
// 61.161 us; speedup vs baseline: 1.2254x; 1.0067x over previous
//
#include <hip/hip_runtime.h>

// Two-dispatch AUCM loss, pair-tiled (R7 structure, best measured 61.6us).
// Change vs R7: 512 blocks = 32 j-blocks x 16 i-tiles; each thread owns TWO
// j's (j, j+256) sharing one LDS read stream of the positive slice ->
// 2x VALU/LDS ratio, half the block ramp, half the redundant tile fetch,
// half the relu partials (1024 -> 512 doubles) for the fin kernel.
//
// Encoded lessons: grid.sync ~25us (R1); any cross-block arrival/finalize
// protocol costs more than a dispatch boundary (R3/R4/R6); redundant
// full-input scans per block lose (R2); hoisted j-loads win (R7).
//
// Math: with a_i = 1 - p_i over positives, n_j = p_j over negatives,
//   loss = [ Nn*Sum(a^2) + 2*Sum(a)*Sum(n) + P*Sum(n^2)       (squared, O(N))
//            + margin * Sum_{i,j} relu(a_i + n_j) ] / (P*Nn)  (pairwise)
//
// No ws zero-init: every ws slot read by kernel B is written by kernel A.
// ws layout:
//   [0    .. 4096)  double reluPart[512]
//   [4096 .. 5120)  double momPart[16][8]  (sumA, sumA2, sumN, sumN2, cnt)

#define TILE  1024
#define NTIL  16     // 16 * 1024 = 16384
#define NJB   32     // 32 blocks * 512 j's = 16384
#define NBLK  (NJB * NTIL)   // 512

__device__ __forceinline__ double wave_reduce_f64(double v) {
    #pragma unroll
    for (int off = 32; off > 0; off >>= 1) v += __shfl_xor(v, off, 64);
    return v;
}

// ---------------------------------------------------------------------------
__global__ __launch_bounds__(256)
void aucm_pair(const float* __restrict__ preds,
               const int* __restrict__ tgt,
               int n,
               double* __restrict__ reluPart,   // [512]
               double* __restrict__ momPart)    // [16][8]
{
    __shared__ __align__(16) float sP[TILE];
    __shared__ int sWaveC[4];
    __shared__ double sRed[4][6];

    const int tid  = threadIdx.x;
    const int lane = tid & 63;
    const int wave = tid >> 6;
    const int b    = blockIdx.x;
    const int jb   = b & (NJB - 1);   // j-block (0..31)
    const int it   = b >> 5;          // i-tile  (0..15)
    const bool doMom = (jb == 0);

    // ---- Issue ALL global loads up front (latency overlap with the scan).
    const int base = it * TILE + (tid << 2);
    const int4   t4 = *reinterpret_cast<const int4*>(&tgt[base]);
    const float4 p4 = *reinterpret_cast<const float4*>(&preds[base]);
    const int j0 = (jb << 9) + tid;      // [0, 16384)
    const int j1 = j0 + 256;
    const int   tj0 = tgt[j0];
    const int   tj1 = tgt[j1];
    const float pj0 = preds[j0];
    const float pj1 = preds[j1];

    const int f0 = (t4.x == 1), f1 = (t4.y == 1),
              f2 = (t4.z == 1), f3 = (t4.w == 1);
    const int c = f0 + f1 + f2 + f3;

    // ---- Deterministic compaction offset: shfl inclusive scan + wave offs.
    int v = c;
    #pragma unroll
    for (int d = 1; d < 64; d <<= 1) {
        const int t = __shfl_up(v, d, 64);
        if (lane >= d) v += t;
    }
    if (lane == 63) sWaveC[wave] = v;
    __syncthreads();
    int wOff = 0;
    #pragma unroll
    for (int w = 0; w < 4; ++w) if (w < wave) wOff += sWaveC[w];
    const int cntP = sWaveC[0] + sWaveC[1] + sWaveC[2] + sWaveC[3];

    int g = wOff + v - c;              // exclusive start, element order kept
    if (f0) sP[g++] = 1.0f - p4.x;
    if (f1) sP[g++] = 1.0f - p4.y;
    if (f2) sP[g++] = 1.0f - p4.z;
    if (f3) sP[g++] = 1.0f - p4.w;

    // ---- Per-tile moments (only the 16 jb==0 blocks), all in double.
    double mA = 0, mA2 = 0, mN = 0, mN2 = 0;
    if (doMom) {
        const float pv[4] = { p4.x, p4.y, p4.z, p4.w };
        const int   fv[4] = { f0, f1, f2, f3 };
        #pragma unroll
        for (int u = 0; u < 4; ++u) {
            if (fv[u]) { const double a = 1.0 - (double)pv[u]; mA += a; mA2 += a * a; }
            else       { const double p = (double)pv[u];       mN += p; mN2 += p * p; }
        }
    }
    __syncthreads();

    // ---- Relu pair loop: 2 j's share one LDS read stream. Per-j element
    //      order identical to R7 (dual f32 accs, <=64-add chunks -> double).
    double accd0 = 0.0, accd1 = 0.0;
    {
        int k = 0;
        while (k < cntP) {
            const int end = min(cntP, k + 64);
            float a0 = 0.f, a1 = 0.f;   // j0
            float b0 = 0.f, b1 = 0.f;   // j1
            for (; k + 8 <= end; k += 8) {
                const float4 v0 = *reinterpret_cast<const float4*>(&sP[k]);
                const float4 v1 = *reinterpret_cast<const float4*>(&sP[k + 4]);
                a0 += fmaxf(v0.x + pj0, 0.f);  b0 += fmaxf(v0.x + pj1, 0.f);
                a1 += fmaxf(v0.y + pj0, 0.f);  b1 += fmaxf(v0.y + pj1, 0.f);
                a0 += fmaxf(v0.z + pj0, 0.f);  b0 += fmaxf(v0.z + pj1, 0.f);
                a1 += fmaxf(v0.w + pj0, 0.f);  b1 += fmaxf(v0.w + pj1, 0.f);
                a0 += fmaxf(v1.x + pj0, 0.f);  b0 += fmaxf(v1.x + pj1, 0.f);
                a1 += fmaxf(v1.y + pj0, 0.f);  b1 += fmaxf(v1.y + pj1, 0.f);
                a0 += fmaxf(v1.z + pj0, 0.f);  b0 += fmaxf(v1.z + pj1, 0.f);
                a1 += fmaxf(v1.w + pj0, 0.f);  b1 += fmaxf(v1.w + pj1, 0.f);
            }
            float at = a0 + a1, bt = b0 + b1;
            for (; k < end; ++k) {
                const float s = sP[k];
                at += fmaxf(s + pj0, 0.f);
                bt += fmaxf(s + pj1, 0.f);
            }
            accd0 += (double)at;       // chunked double flush (<=64 f32 adds)
            accd1 += (double)bt;
        }
    }
    if (tj0 != 0) accd0 = 0.0;         // j0 is a positive: no pairs
    if (tj1 != 0) accd1 = 0.0;

    double r = wave_reduce_f64(accd0 + accd1);
    if (lane == 0) sRed[wave][0] = r;
    if (doMom) {
        const double rA  = wave_reduce_f64(mA);
        const double rA2 = wave_reduce_f64(mA2);
        const double rN  = wave_reduce_f64(mN);
        const double rN2 = wave_reduce_f64(mN2);
        if (lane == 0) {
            sRed[wave][1] = rA; sRed[wave][2] = rA2;
            sRed[wave][3] = rN; sRed[wave][4] = rN2;
        }
    }
    __syncthreads();
    if (tid == 0) {
        reluPart[b] = sRed[0][0] + sRed[1][0] + sRed[2][0] + sRed[3][0];
        if (doMom) {
            double tA = 0, tA2 = 0, tN = 0, tN2 = 0;
            #pragma unroll
            for (int w = 0; w < 4; ++w) {
                tA += sRed[w][1]; tA2 += sRed[w][2];
                tN += sRed[w][3]; tN2 += sRed[w][4];
            }
            momPart[it * 8 + 0] = tA;  momPart[it * 8 + 1] = tA2;
            momPart[it * 8 + 2] = tN;  momPart[it * 8 + 3] = tN2;
            momPart[it * 8 + 4] = (double)cntP;
        }
    }
}

// ---------------------------------------------------------------------------
__global__ __launch_bounds__(256)
void aucm_fin(const double* __restrict__ reluPart,
              const double* __restrict__ momPart,
              int n, float* __restrict__ out, float margin)
{
    __shared__ double sRedR[4];
    const int tid  = threadIdx.x;
    const int lane = tid & 63;
    const int wave = tid >> 6;

    // Relu partials: 512 doubles, 2 per thread (deterministic order).
    double r = reluPart[tid] + reluPart[tid + 256];
    r = wave_reduce_f64(r);
    if (lane == 0) sRedR[wave] = r;

    // Moments: 16 tiles x 5 values, handled by wave 0 lanes 0..15.
    double mA = 0, mA2 = 0, mN = 0, mN2 = 0, pc = 0;
    if (tid < NTIL) {
        mA  = momPart[tid * 8 + 0]; mA2 = momPart[tid * 8 + 1];
        mN  = momPart[tid * 8 + 2]; mN2 = momPart[tid * 8 + 3];
        pc  = momPart[tid * 8 + 4];
    }
    if (wave == 0) {
        mA  = wave_reduce_f64(mA);  mA2 = wave_reduce_f64(mA2);
        mN  = wave_reduce_f64(mN);  mN2 = wave_reduce_f64(mN2);
        pc  = wave_reduce_f64(pc);
    }
    __syncthreads();
    if (tid == 0) {
        const double tR = sRedR[0] + sRedR[1] + sRedR[2] + sRedR[3];
        const double P  = pc;
        const double Nn = (double)n - P;
        const double sq = Nn * mA2 + 2.0 * mA * mN + P * mN2;
        out[0] = (float)((sq + (double)margin * tR) / (P * Nn));
    }
}

// ---------------------------------------------------------------------------
extern "C" void kernel_launch(void* const* d_in, const int* in_sizes, int n_in,
                              void* d_out, int out_size, void* d_ws, size_t ws_size,
                              hipStream_t stream) {
    const float* preds = (const float*)d_in[0];
    const int*   tgt   = (const int*)d_in[1];
    float* out = (float*)d_out;
    const int n = in_sizes[0];   // 16384 = NTIL*TILE = NJB*512

    char* ws = (char*)d_ws;
    double* reluPart = (double*)(ws + 0);
    double* momPart  = (double*)(ws + 4096);

    aucm_pair<<<NBLK, 256, 0, stream>>>(preds, tgt, n, reluPart, momPart);
    aucm_fin<<<1, 256, 0, stream>>>(reluPart, momPart, n, out, 1.0f /*MARGIN*/);
}